// Round 7
// baseline (259.991 us; speedup 1.0000x reference)
//
#include <hip/hip_runtime.h>

#define HH 4
#define CC 128
#define NEG_SLOPE 0.2f
#define NPB 8

typedef float v2f __attribute__((ext_vector_type(2)));

static __device__ __forceinline__ v2f pkfma(v2f a, v2f b, v2f c) {
#if __has_builtin(__builtin_elementwise_fma)
    return __builtin_elementwise_fma(a, b, c);
#else
    return (v2f){fmaf(a.x, b.x, c.x), fmaf(a.y, b.y, c.y)};
#endif
}
static __device__ __forceinline__ v2f vabs(v2f u) {
#if __has_builtin(__builtin_elementwise_abs)
    return __builtin_elementwise_abs(u);
#else
    return (v2f){__builtin_fabsf(u.x), __builtin_fabsf(u.y)};
#endif
}

static inline size_t roundup256(size_t x) { return (x + 255) & ~(size_t)255; }

// ---------------- prep: mean(edge_attr) + in-degree hist + weight pack + Lin
// pair-major pack: record per (bh, q=pair): 16 floats
//   {A0,A1,B0,B1,C0,C1,D0,D1,E0,E1,F0,F1,G'0,G'1,0,0}, G'=0.4*att
// Lin[bh][6] = 0.6 * sum_c att_c * {A,B,C,D,E,F}_c
__global__ __launch_bounds__(256) void prep_kernel(
    const int* __restrict__ ei, const float* __restrict__ eattr,
    float* __restrict__ meansum, float* __restrict__ Lin, int* __restrict__ cnt,
    const float* __restrict__ Wsrc0, const float* __restrict__ bsrc0,
    const float* __restrict__ Wdst0, const float* __restrict__ bdst0,
    const float* __restrict__ Wedge0, const float* __restrict__ att0,
    const float* __restrict__ Wsrc1, const float* __restrict__ bsrc1,
    const float* __restrict__ Wdst1, const float* __restrict__ bdst1,
    const float* __restrict__ Wedge1, const float* __restrict__ att1,
    float* __restrict__ packed, int E)
{
    int tid = blockIdx.x * 256 + threadIdx.x;
    float s = 0.f;
    if (tid < E) {
        atomicAdd(&cnt[ei[E + tid]], 1);
        s = eattr[tid];
    }
    #pragma unroll
    for (int off = 32; off > 0; off >>= 1) s += __shfl_down(s, off, 64);
    __shared__ float wsum[4];
    int lane = threadIdx.x & 63, wid = threadIdx.x >> 6;
    if (lane == 0) wsum[wid] = s;
    __syncthreads();
    if (threadIdx.x == 0)
        atomicAdd(meansum, wsum[0] + wsum[1] + wsum[2] + wsum[3]);

    if (tid < 1024) {
        int b = tid >> 9;
        int hc = tid & 511;
        int c = hc & 127;
        int h = hc >> 7;
        int bh = b * 4 + h;
        const float* Ws = b ? Wsrc1 : Wsrc0;
        const float* bs = b ? bsrc1 : bsrc0;
        const float* Wd = b ? Wdst1 : Wdst0;
        const float* bd = b ? bdst1 : bdst0;
        const float* We = b ? Wedge1 : Wedge0;
        const float* at = b ? att1 : att0;
        float A = Ws[hc], B = Ws[512 + hc];
        float C = Wd[hc], D = Wd[512 + hc];
        float Ec = We[hc];
        float F = bs[hc] + bd[hc];
        float a = at[hc];
        int q = c >> 1, sub = c & 1;
        float* r = packed + ((size_t)(bh * 64 + q)) * 16 + sub;
        r[0] = A; r[2] = B; r[4] = C; r[6] = D;
        r[8] = Ec; r[10] = F; r[12] = 0.4f * a; r[14] = 0.f;
        float sa = 0.6f * a;
        atomicAdd(&Lin[bh * 6 + 0], sa * A);
        atomicAdd(&Lin[bh * 6 + 1], sa * B);
        atomicAdd(&Lin[bh * 6 + 2], sa * C);
        atomicAdd(&Lin[bh * 6 + 3], sa * D);
        atomicAdd(&Lin[bh * 6 + 4], sa * Ec);
        atomicAdd(&Lin[bh * 6 + 5], sa * F);
    }
}

// ---------------- scan: exclusive prefix over (cnt+1), seeds cur ------------
__global__ __launch_bounds__(1024) void scan_kernel(const int* __restrict__ cnt,
                                                    int* __restrict__ rowptr,
                                                    int* __restrict__ cur, int N) {
    const int CH = 32;  // covers N up to 32768
    int t = threadIdx.x;
    int base = t * CH;
    int local[CH];
    int s = 0;
    #pragma unroll
    for (int i = 0; i < CH; ++i) {
        int idx = base + i;
        int v = (idx < N) ? cnt[idx] + 1 : 0;  // +1 = self loop
        local[i] = s;
        s += v;
    }
    __shared__ int sums[1024];
    sums[t] = s;
    __syncthreads();
    for (int off = 1; off < 1024; off <<= 1) {
        int v = (t >= off) ? sums[t - off] : 0;
        __syncthreads();
        sums[t] += v;
        __syncthreads();
    }
    int excl = sums[t] - s;
    #pragma unroll
    for (int i = 0; i < CH; ++i) {
        int idx = base + i;
        if (idx < N) {
            int v = excl + local[i];
            rowptr[idx] = v;
            cur[idx] = v;
        }
    }
    if (t == 1023) rowptr[N] = excl + s;
}

// ---------------- scatter: build CSR edge records {xs,xd} + ea --------------
__global__ __launch_bounds__(256) void scatter_kernel(
    const int* __restrict__ ei, const float* __restrict__ x,
    const float* __restrict__ eattr, const float* __restrict__ meansum,
    int* __restrict__ cur, float4* __restrict__ ed4, float* __restrict__ ea1,
    int N, int E) {
    int e = blockIdx.x * 256 + threadIdx.x;
    int Etot = E + N;
    if (e >= Etot) return;
    int src, dst;
    float ea;
    if (e < E) { src = ei[e]; dst = ei[E + e]; ea = eattr[e]; }
    else       { src = e - E; dst = src; ea = meansum[0] / (float)E; }
    int pos = atomicAdd(&cur[dst], 1);
    const float2* x2 = (const float2*)x;
    float2 xs = x2[src];
    float2 xd = x2[dst];
    ed4[pos] = make_float4(xs.x, xs.y, xd.x, xd.y);
    ea1[pos] = ea;
}

// ---------------- logits: weights pinned in registers via asm ---------------
// lane = bh*8 + cg; lane owns pairs q = cg*8..cg*8+7 of its bh (channels 16cg..16cg+15)
// logit = Lin[bh].(xs0,xs1,xd0,xd1,ea,1) + sum_c 0.4*att_c*|u_c|
__global__ __launch_bounds__(256)
__attribute__((amdgpu_waves_per_eu(2, 4)))
void logits_kernel(
    const float4* __restrict__ ed4,
    const float* __restrict__ ea1,
    const float* __restrict__ Lin,
    const float4* __restrict__ pw,   // pair-major packed, 4 float4 per record
    float* __restrict__ p8, int EtotPad)
{
    __shared__ __align__(16) float zl[4][64][8];
    int t = threadIdx.x;
    int wid = t >> 6, lane = t & 63;
    int bh = lane >> 3, cg = lane & 7;

    // per-lane weights: 8 pairs x 7 v2f, loaded from 512 contiguous bytes
    v2f WA[8], WB[8], WC[8], WD[8], WE[8], WF[8], WG[8];
    {
        int rbase = (bh * 64 + cg * 8) * 4;  // float4 index
        #pragma unroll
        for (int p = 0; p < 8; ++p) {
            float4 t0 = pw[rbase + p * 4 + 0];
            float4 t1 = pw[rbase + p * 4 + 1];
            float4 t2 = pw[rbase + p * 4 + 2];
            float4 t3 = pw[rbase + p * 4 + 3];
            WA[p] = (v2f){t0.x, t0.y};
            WB[p] = (v2f){t0.z, t0.w};
            WC[p] = (v2f){t1.x, t1.y};
            WD[p] = (v2f){t1.z, t1.w};
            WE[p] = (v2f){t2.x, t2.y};
            WF[p] = (v2f){t2.z, t2.w};
            WG[p] = (v2f){t3.x, t3.y};
        }
    }
    // pin weights in VGPRs: compiler cannot rematerialize from memory past this
    #pragma unroll
    for (int p = 0; p < 8; ++p) {
        asm volatile("" : "+v"(WA[p]), "+v"(WB[p]), "+v"(WC[p]), "+v"(WD[p]),
                          "+v"(WE[p]), "+v"(WF[p]), "+v"(WG[p]));
    }
    float L0 = Lin[bh * 6 + 0], L1 = Lin[bh * 6 + 1], L2 = Lin[bh * 6 + 2];
    float L3 = Lin[bh * 6 + 3], L4 = Lin[bh * 6 + 4], L5 = Lin[bh * 6 + 5];

    int base = (blockIdx.x * 4 + wid) * 64;
    if (base >= EtotPad) return;
    // stage 64 edges (arrays are padded; garbage beyond Etot is harmless)
    {
        int i = base + lane;
        float4 ev = ed4[i];
        float ea = ea1[i];
        *(float4*)&zl[wid][lane][0] = ev;
        *(float4*)&zl[wid][lane][4] = make_float4(ea, 0.f, 0.f, 0.f);
    }
    __syncthreads();

    #pragma unroll 8
    for (int e = 0; e < 64; ++e) {
        float4 xv = *(const float4*)&zl[wid][e][0];
        float eas = zl[wid][e][4];
        v2f xs0 = {xv.x, xv.x}, xs1 = {xv.y, xv.y};
        v2f xd0 = {xv.z, xv.z}, xd1 = {xv.w, xv.w};
        v2f eav = {eas, eas};
        v2f acc = {0.f, 0.f};
        #pragma unroll
        for (int p = 0; p < 8; ++p) {
            v2f u = pkfma(WE[p], eav, WF[p]);
            u = pkfma(WA[p], xs0, u);
            u = pkfma(WB[p], xs1, u);
            u = pkfma(WC[p], xd0, u);
            u = pkfma(WD[p], xd1, u);
            acc = pkfma(WG[p], vabs(u), acc);
        }
        float s = acc.x + acc.y;
        s += __shfl_xor(s, 1);
        s += __shfl_xor(s, 2);
        s += __shfl_xor(s, 4);
        if (cg == (e & 7)) {
            float lg = fmaf(L0, xv.x, fmaf(L1, xv.y, fmaf(L2, xv.z,
                       fmaf(L3, xv.w, fmaf(L4, eas, L5))))) + s;
            p8[(size_t)(base + e) * 8 + bh] = __expf(lg);
        }
    }
}

// ---------------- nodeS: per-node gather (coalesced CSR reads) --------------
__global__ __launch_bounds__(256) void nodeS_kernel(
    const int* __restrict__ rowptr, const float4* __restrict__ ed4,
    const float* __restrict__ p8, float* __restrict__ S, int N)
{
    int t = threadIdx.x;
    int g = t >> 3, bh = t & 7;
    int n = blockIdx.x * 32 + g;
    if (n >= N) return;
    int beg = rowptr[n], end = rowptr[n + 1];
    float s0 = 0.f, s1 = 0.f, sb = 0.f;
    for (int i = beg; i < end; ++i) {
        float4 ed = ed4[i];
        float p = p8[(size_t)i * 8 + bh];
        s0 = fmaf(p, ed.x, s0);
        s1 = fmaf(p, ed.y, s1);
        sb += p;
    }
    float* Sp = S + (size_t)n * 24 + bh * 3;
    Sp[0] = s0;
    Sp[1] = s1;
    Sp[2] = sb;
}

// ---------------- node: reconstruction + fuse matvec ------------------------
__global__ __launch_bounds__(256) void node_kernel(
    const float* __restrict__ x,
    const float* __restrict__ S,
    const float* __restrict__ Wsrc0, const float* __restrict__ bsrc0,
    const float* __restrict__ bias0, const float* __restrict__ Wres0,
    const float* __restrict__ Wsrc1, const float* __restrict__ bsrc1,
    const float* __restrict__ bias1, const float* __restrict__ Wres1,
    const float* __restrict__ Wfuse, const float* __restrict__ bfuse,
    float* __restrict__ out, int N)
{
    __shared__ __align__(16) float hbuf[NPB][2 * CC];
    int t = threadIdx.x;
    int c = t & (CC - 1);
    int half = t >> 7;  // 0 or 1
    int n0 = blockIdx.x * NPB;

    float w00[HH], w01[HH], wb0[HH], w10[HH], w11[HH], wb1[HH];
    #pragma unroll
    for (int h = 0; h < HH; ++h) {
        w00[h] = Wsrc0[h * CC + c];
        w01[h] = Wsrc0[512 + h * CC + c];
        wb0[h] = bsrc0[h * CC + c];
        w10[h] = Wsrc1[h * CC + c];
        w11[h] = Wsrc1[512 + h * CC + c];
        wb1[h] = bsrc1[h * CC + c];
    }
    float bi0 = bias0[c], bi1 = bias1[c];
    float r00 = Wres0[c], r01 = Wres0[CC + c];
    float r10 = Wres1[c], r11 = Wres1[CC + c];

    for (int ni = half; ni < NPB; ni += 2) {
        int n = n0 + ni;
        if (n < N) {
            float x0 = x[2 * n], x1 = x[2 * n + 1];
            const float* Sp = S + (size_t)n * 24;
            float h0v, h1v;
            {
                float acc = 0.f;
                #pragma unroll
                for (int h = 0; h < HH; ++h) {
                    float s0 = Sp[h * 3 + 0];
                    float s1 = Sp[h * 3 + 1];
                    float sb = Sp[h * 3 + 2];
                    float num = fmaf(w00[h], s0, fmaf(w01[h], s1, wb0[h] * sb));
                    acc += num / (sb + 1e-16f);
                }
                float o = fmaxf(acc * 0.25f + bi0, 0.f);
                h0v = o + x0 * r00 + x1 * r01;
            }
            {
                float acc = 0.f;
                #pragma unroll
                for (int h = 0; h < HH; ++h) {
                    float s0 = Sp[12 + h * 3 + 0];
                    float s1 = Sp[12 + h * 3 + 1];
                    float sb = Sp[12 + h * 3 + 2];
                    float num = fmaf(w10[h], s0, fmaf(w11[h], s1, wb1[h] * sb));
                    acc += num / (sb + 1e-16f);
                }
                float o = fmaxf(acc * 0.25f + bi1, 0.f);
                h1v = o + x0 * r10 + x1 * r11;
            }
            hbuf[ni][c] = h0v;
            hbuf[ni][CC + c] = h1v;
        }
    }
    __syncthreads();

    float acc[4];
    float bf = bfuse[c];
    #pragma unroll
    for (int j = 0; j < 4; ++j) acc[j] = bf;

    for (int i = 0; i < 2 * CC; i += 4) {
        float wv0 = Wfuse[(i + 0) * CC + c];
        float wv1 = Wfuse[(i + 1) * CC + c];
        float wv2 = Wfuse[(i + 2) * CC + c];
        float wv3 = Wfuse[(i + 3) * CC + c];
        #pragma unroll
        for (int j = 0; j < 4; ++j) {
            int ni = half * 4 + j;
            float4 hv = *reinterpret_cast<const float4*>(&hbuf[ni][i]);
            acc[j] = fmaf(hv.x, wv0, fmaf(hv.y, wv1,
                     fmaf(hv.z, wv2, fmaf(hv.w, wv3, acc[j]))));
        }
    }
    #pragma unroll
    for (int j = 0; j < 4; ++j) {
        int n = n0 + half * 4 + j;
        if (n < N) out[n * CC + c] = fmaxf(acc[j], 0.f);
    }
}

extern "C" void kernel_launch(void* const* d_in, const int* in_sizes, int n_in,
                              void* d_out, int out_size, void* d_ws, size_t ws_size,
                              hipStream_t stream) {
    const float* x      = (const float*)d_in[0];
    const int*   ei     = (const int*)d_in[1];
    const float* eattr  = (const float*)d_in[2];
    const float* Wsrc0  = (const float*)d_in[3];
    const float* bsrc0  = (const float*)d_in[4];
    const float* Wdst0  = (const float*)d_in[5];
    const float* bdst0  = (const float*)d_in[6];
    const float* Wedge0 = (const float*)d_in[7];
    const float* att0   = (const float*)d_in[8];
    const float* bias0  = (const float*)d_in[9];
    const float* Wres0  = (const float*)d_in[10];
    const float* Wsrc1  = (const float*)d_in[11];
    const float* bsrc1  = (const float*)d_in[12];
    const float* Wdst1  = (const float*)d_in[13];
    const float* bdst1  = (const float*)d_in[14];
    const float* Wedge1 = (const float*)d_in[15];
    const float* att1   = (const float*)d_in[16];
    const float* bias1  = (const float*)d_in[17];
    const float* Wres1  = (const float*)d_in[18];
    const float* Wfuse  = (const float*)d_in[19];
    const float* bfuse  = (const float*)d_in[20];
    float* out = (float*)d_out;

    int N = in_sizes[0] / 2;   // x is (N,2)
    int E = in_sizes[1] / 2;   // edge_index is (2,E)
    int Etot = E + N;
    int EtotPad = (Etot + 255) & ~255;

    // workspace layout; zero region = meansum(0..4) + Lin(64..256) + cnt
    size_t off = 0;
    float* meansum = (float*)((char*)d_ws + off);
    float* Lin     = (float*)((char*)d_ws + 64);   off += 256;
    int*   cnt     = (int*)((char*)d_ws + off);    off += roundup256((size_t)N * sizeof(int));
    size_t zero_bytes = off;
    int*   cur     = (int*)((char*)d_ws + off);    off += roundup256((size_t)N * sizeof(int));
    int*   rowptr  = (int*)((char*)d_ws + off);    off += roundup256((size_t)(N + 1) * sizeof(int));
    float* packed  = (float*)((char*)d_ws + off);  off += roundup256(8 * 64 * 16 * sizeof(float));
    float4* ed4    = (float4*)((char*)d_ws + off); off += roundup256((size_t)EtotPad * sizeof(float4));
    float* ea1     = (float*)((char*)d_ws + off);  off += roundup256((size_t)EtotPad * sizeof(float));
    float* p8      = (float*)((char*)d_ws + off);  off += roundup256((size_t)EtotPad * 8 * sizeof(float));
    float* S       = (float*)((char*)d_ws + off);  off += roundup256((size_t)24 * N * sizeof(float));

    hipMemsetAsync(d_ws, 0, zero_bytes, stream);

    prep_kernel<<<(E + 255) / 256, 256, 0, stream>>>(
        ei, eattr, meansum, Lin, cnt,
        Wsrc0, bsrc0, Wdst0, bdst0, Wedge0, att0,
        Wsrc1, bsrc1, Wdst1, bdst1, Wedge1, att1,
        packed, E);

    scan_kernel<<<1, 1024, 0, stream>>>(cnt, rowptr, cur, N);

    scatter_kernel<<<(Etot + 255) / 256, 256, 0, stream>>>(
        ei, x, eattr, meansum, cur, ed4, ea1, N, E);

    int nblk = EtotPad / 256;
    logits_kernel<<<nblk, 256, 0, stream>>>(
        ed4, ea1, Lin, (const float4*)packed, p8, EtotPad);

    nodeS_kernel<<<(N + 31) / 32, 256, 0, stream>>>(rowptr, ed4, p8, S, N);

    node_kernel<<<(N + NPB - 1) / NPB, 256, 0, stream>>>(
        x, S,
        Wsrc0, bsrc0, bias0, Wres0,
        Wsrc1, bsrc1, bias1, Wres1,
        Wfuse, bfuse, out, N);
}

// Round 8
// 226.162 us; speedup vs baseline: 1.1496x; 1.1496x over previous
//
#include <hip/hip_runtime.h>

#define HH 4
#define CC 128
#define NPB 16

typedef float v2f __attribute__((ext_vector_type(2)));

static __device__ __forceinline__ v2f pkfma(v2f a, v2f b, v2f c) {
#if __has_builtin(__builtin_elementwise_fma)
    return __builtin_elementwise_fma(a, b, c);
#else
    return (v2f){fmaf(a.x, b.x, c.x), fmaf(a.y, b.y, c.y)};
#endif
}
// scalar (SGPR) coefficient times vector plus vector: 1 scalar operand per inst
static __device__ __forceinline__ v2f sfma(float s, v2f v, v2f c) {
    return pkfma((v2f){s, s}, v, c);
}
static __device__ __forceinline__ v2f vabs2(v2f u) {
#if __has_builtin(__builtin_elementwise_abs)
    return __builtin_elementwise_abs(u);
#else
    return (v2f){__builtin_fabsf(u.x), __builtin_fabsf(u.y)};
#endif
}

static inline size_t roundup256(size_t x) { return (x + 255) & ~(size_t)255; }

// ---------------- prep: mean(edge_attr) + in-degree hist + pack + Lin -------
// record per (bh,c), c-major: {A,B,C,D,E,F=bsrc+bdst,G'=0.4*att,0}
// Lin[bh][6] = 0.6 * sum_c att_c * {A,B,C,D,E,F}_c   (deterministic shfl reduce)
__global__ __launch_bounds__(256) void prep_kernel(
    const int* __restrict__ ei, const float* __restrict__ eattr,
    float* __restrict__ meansum, float* __restrict__ Lin, int* __restrict__ cnt,
    const float* __restrict__ Wsrc0, const float* __restrict__ bsrc0,
    const float* __restrict__ Wdst0, const float* __restrict__ bdst0,
    const float* __restrict__ Wedge0, const float* __restrict__ att0,
    const float* __restrict__ Wsrc1, const float* __restrict__ bsrc1,
    const float* __restrict__ Wdst1, const float* __restrict__ bdst1,
    const float* __restrict__ Wedge1, const float* __restrict__ att1,
    float* __restrict__ packed, int E)
{
    int tid = blockIdx.x * 256 + threadIdx.x;
    int lane = threadIdx.x & 63, wid = threadIdx.x >> 6;
    float s = 0.f;
    if (tid < E) {
        atomicAdd(&cnt[ei[E + tid]], 1);
        s = eattr[tid];
    }
    #pragma unroll
    for (int off = 32; off > 0; off >>= 1) s += __shfl_down(s, off, 64);
    __shared__ float wsum[4];
    if (lane == 0) wsum[wid] = s;
    __syncthreads();
    if (threadIdx.x == 0)
        atomicAdd(meansum, wsum[0] + wsum[1] + wsum[2] + wsum[3]);

    if (blockIdx.x < 4) {  // tid < 1024: one thread per (b,h,c)
        int b = tid >> 9;
        int hc = tid & 511;
        int c = hc & 127;
        int h = hc >> 7;
        int bh = b * 4 + h;
        const float* Ws = b ? Wsrc1 : Wsrc0;
        const float* bs = b ? bsrc1 : bsrc0;
        const float* Wd = b ? Wdst1 : Wdst0;
        const float* bd = b ? bdst1 : bdst0;
        const float* We = b ? Wedge1 : Wedge0;
        const float* at = b ? att1 : att0;
        float A = Ws[hc], B = Ws[512 + hc];
        float C = Wd[hc], D = Wd[512 + hc];
        float Ec = We[hc];
        float F = bs[hc] + bd[hc];
        float a = at[hc];
        float4* r = (float4*)(packed + ((size_t)(bh * 128 + c)) * 8);
        r[0] = make_float4(A, B, C, D);
        r[1] = make_float4(Ec, F, 0.4f * a, 0.f);
        // deterministic Lin: shuffle-reduce each of 6 values over the wave;
        // this block's 4 waves are exactly (bh pair) x (c halves)
        float sa = 0.6f * a;
        float vals[6] = {sa * A, sa * B, sa * C, sa * D, sa * Ec, sa * F};
        #pragma unroll
        for (int k = 0; k < 6; ++k) {
            float v = vals[k];
            #pragma unroll
            for (int off = 32; off > 0; off >>= 1) v += __shfl_down(v, off, 64);
            vals[k] = v;
        }
        __shared__ float Ls[4][6];
        if (lane == 0) {
            #pragma unroll
            for (int k = 0; k < 6; ++k) Ls[wid][k] = vals[k];
        }
        __syncthreads();
        if (threadIdx.x < 12) {
            int w2 = threadIdx.x / 6;       // bh_local 0/1
            int k = threadIdx.x % 6;
            int bhg = blockIdx.x * 2 + w2;
            Lin[bhg * 6 + k] = Ls[w2 * 2][k] + Ls[w2 * 2 + 1][k];
        }
    }
}

// ---------------- scan: exclusive prefix over (cnt+1), seeds cur ------------
__global__ __launch_bounds__(1024) void scan_kernel(const int* __restrict__ cnt,
                                                    int* __restrict__ rowptr,
                                                    int* __restrict__ cur, int N) {
    const int CH = 32;  // covers N up to 32768
    int t = threadIdx.x;
    int base = t * CH;
    int local[CH];
    int s = 0;
    #pragma unroll
    for (int i = 0; i < CH; ++i) {
        int idx = base + i;
        int v = (idx < N) ? cnt[idx] + 1 : 0;  // +1 = self loop
        local[i] = s;
        s += v;
    }
    __shared__ int sums[1024];
    sums[t] = s;
    __syncthreads();
    for (int off = 1; off < 1024; off <<= 1) {
        int v = (t >= off) ? sums[t - off] : 0;
        __syncthreads();
        sums[t] += v;
        __syncthreads();
    }
    int excl = sums[t] - s;
    #pragma unroll
    for (int i = 0; i < CH; ++i) {
        int idx = base + i;
        if (idx < N) {
            int v = excl + local[i];
            rowptr[idx] = v;
            cur[idx] = v;
        }
    }
    if (t == 1023) rowptr[N] = excl + s;
}

// ---------------- scatter: build CSR edge records {xs,xd} + ea --------------
__global__ __launch_bounds__(256) void scatter_kernel(
    const int* __restrict__ ei, const float* __restrict__ x,
    const float* __restrict__ eattr, const float* __restrict__ meansum,
    int* __restrict__ cur, float4* __restrict__ ed4, float* __restrict__ ea1,
    int N, int E) {
    int e = blockIdx.x * 256 + threadIdx.x;
    int Etot = E + N;
    if (e >= Etot) return;
    int src, dst;
    float ea;
    if (e < E) { src = ei[e]; dst = ei[E + e]; ea = eattr[e]; }
    else       { src = e - E; dst = src; ea = meansum[0] / (float)E; }
    int pos = atomicAdd(&cur[dst], 1);
    const float2* x2 = (const float2*)x;
    float2 xs = x2[src];
    float2 xd = x2[dst];
    ed4[pos] = make_float4(xs.x, xs.y, xd.x, xd.y);
    ea1[pos] = ea;
}

// ---------------- logits: SGPR-streamed weights, 2 edges per lane -----------
// logit = Lin[bh].(xs0,xs1,xd0,xd1,ea,1) + sum_c G'_c * |u_c|
// p8[i*8+bh] = exp(logit) at CSR position i.
__global__ __launch_bounds__(256) void logits_kernel(
    const float4* __restrict__ ed4,
    const float* __restrict__ ea1,
    const float* __restrict__ Lin,
    const float4* __restrict__ pw,   // (bh*128+c)*2 float4: {A,B,C,D},{E,F,G',0}
    float* __restrict__ p8, int EtotPad)
{
    int t = threadIdx.x;
    int wid = t >> 6, lane = t & 63;
    int base = (blockIdx.x * 4 + wid) * 128;   // 128 edges per wave

    int iA = base + lane, iB = base + 64 + lane;
    float4 eA = ed4[iA], eB = ed4[iB];
    float aA = ea1[iA], aB = ea1[iB];

    v2f xs0 = {eA.x, eB.x}, xs1 = {eA.y, eB.y};
    v2f xd0 = {eA.z, eB.z}, xd1 = {eA.w, eB.w};
    v2f ea2 = {aA, aB};
    v2f one2 = {1.f, 1.f};

    v2f accs[8];
    #pragma unroll
    for (int bh = 0; bh < 8; ++bh) {
        const float4* wp = pw + (size_t)bh * 256;
        v2f acc = {0.f, 0.f};
        #pragma unroll 8
        for (int c = 0; c < 128; ++c) {
            float4 w0 = wp[2 * c];       // uniform -> s_load
            float4 w1 = wp[2 * c + 1];   // uniform -> s_load
            v2f u = sfma(w1.y, one2, (v2f){0.f, 0.f});  // F
            u = sfma(w1.x, ea2, u);                      // + E*ea
            u = sfma(w0.x, xs0, u);
            u = sfma(w0.y, xs1, u);
            u = sfma(w0.z, xd0, u);
            u = sfma(w0.w, xd1, u);
            acc = sfma(w1.z, vabs2(u), acc);             // + G'*|u|
        }
        accs[bh] = acc;
    }

    float pA[8], pB[8];
    #pragma unroll
    for (int bh = 0; bh < 8; ++bh) {
        const float* Lp = Lin + bh * 6;   // uniform -> s_load
        float l0 = Lp[0], l1 = Lp[1], l2 = Lp[2], l3 = Lp[3], l4 = Lp[4], l5 = Lp[5];
        float lgA = fmaf(l0, eA.x, fmaf(l1, eA.y, fmaf(l2, eA.z,
                    fmaf(l3, eA.w, fmaf(l4, aA, l5))))) + accs[bh].x;
        float lgB = fmaf(l0, eB.x, fmaf(l1, eB.y, fmaf(l2, eB.z,
                    fmaf(l3, eB.w, fmaf(l4, aB, l5))))) + accs[bh].y;
        pA[bh] = __expf(lgA);
        pB[bh] = __expf(lgB);
    }
    float4* oA = (float4*)&p8[(size_t)iA * 8];
    oA[0] = make_float4(pA[0], pA[1], pA[2], pA[3]);
    oA[1] = make_float4(pA[4], pA[5], pA[6], pA[7]);
    float4* oB = (float4*)&p8[(size_t)iB * 8];
    oB[0] = make_float4(pB[0], pB[1], pB[2], pB[3]);
    oB[1] = make_float4(pB[4], pB[5], pB[6], pB[7]);
}

// ---------------- nodeS: per-node gather (coalesced CSR reads) --------------
__global__ __launch_bounds__(256) void nodeS_kernel(
    const int* __restrict__ rowptr, const float4* __restrict__ ed4,
    const float* __restrict__ p8, float* __restrict__ S, int N)
{
    int t = threadIdx.x;
    int g = t >> 3, bh = t & 7;
    int n = blockIdx.x * 32 + g;
    if (n >= N) return;
    int beg = rowptr[n], end = rowptr[n + 1];
    float s0 = 0.f, s1 = 0.f, sb = 0.f;
    for (int i = beg; i < end; ++i) {
        float4 ed = ed4[i];
        float p = p8[(size_t)i * 8 + bh];
        s0 = fmaf(p, ed.x, s0);
        s1 = fmaf(p, ed.y, s1);
        sb += p;
    }
    float* Sp = S + (size_t)n * 24 + bh * 3;
    Sp[0] = s0;
    Sp[1] = s1;
    Sp[2] = sb;
}

// ---------------- node: reconstruction + fuse matvec ------------------------
__global__ __launch_bounds__(256) void node_kernel(
    const float* __restrict__ x,
    const float* __restrict__ S,
    const float* __restrict__ Wsrc0, const float* __restrict__ bsrc0,
    const float* __restrict__ bias0, const float* __restrict__ Wres0,
    const float* __restrict__ Wsrc1, const float* __restrict__ bsrc1,
    const float* __restrict__ bias1, const float* __restrict__ Wres1,
    const float* __restrict__ Wfuse, const float* __restrict__ bfuse,
    float* __restrict__ out, int N)
{
    __shared__ __align__(16) float hbuf[NPB][2 * CC];
    int t = threadIdx.x;
    int c = t & (CC - 1);
    int half = t >> 7;  // 0 or 1
    int n0 = blockIdx.x * NPB;

    float w00[HH], w01[HH], wb0[HH], w10[HH], w11[HH], wb1[HH];
    #pragma unroll
    for (int h = 0; h < HH; ++h) {
        w00[h] = Wsrc0[h * CC + c];
        w01[h] = Wsrc0[512 + h * CC + c];
        wb0[h] = bsrc0[h * CC + c];
        w10[h] = Wsrc1[h * CC + c];
        w11[h] = Wsrc1[512 + h * CC + c];
        wb1[h] = bsrc1[h * CC + c];
    }
    float bi0 = bias0[c], bi1 = bias1[c];
    float r00 = Wres0[c], r01 = Wres0[CC + c];
    float r10 = Wres1[c], r11 = Wres1[CC + c];

    for (int ni = half; ni < NPB; ni += 2) {
        int n = n0 + ni;
        if (n < N) {
            float x0 = x[2 * n], x1 = x[2 * n + 1];
            const float* Sp = S + (size_t)n * 24;
            float h0v, h1v;
            {
                float acc = 0.f;
                #pragma unroll
                for (int h = 0; h < HH; ++h) {
                    float s0 = Sp[h * 3 + 0];
                    float s1 = Sp[h * 3 + 1];
                    float sb = Sp[h * 3 + 2];
                    float num = fmaf(w00[h], s0, fmaf(w01[h], s1, wb0[h] * sb));
                    acc += num / (sb + 1e-16f);
                }
                float o = fmaxf(acc * 0.25f + bi0, 0.f);
                h0v = o + x0 * r00 + x1 * r01;
            }
            {
                float acc = 0.f;
                #pragma unroll
                for (int h = 0; h < HH; ++h) {
                    float s0 = Sp[12 + h * 3 + 0];
                    float s1 = Sp[12 + h * 3 + 1];
                    float sb = Sp[12 + h * 3 + 2];
                    float num = fmaf(w10[h], s0, fmaf(w11[h], s1, wb1[h] * sb));
                    acc += num / (sb + 1e-16f);
                }
                float o = fmaxf(acc * 0.25f + bi1, 0.f);
                h1v = o + x0 * r10 + x1 * r11;
            }
            hbuf[ni][c] = h0v;
            hbuf[ni][CC + c] = h1v;
        }
    }
    __syncthreads();

    float acc[NPB / 2];
    float bf = bfuse[c];
    #pragma unroll
    for (int j = 0; j < NPB / 2; ++j) acc[j] = bf;

    for (int i = 0; i < 2 * CC; i += 4) {
        float wv0 = Wfuse[(i + 0) * CC + c];
        float wv1 = Wfuse[(i + 1) * CC + c];
        float wv2 = Wfuse[(i + 2) * CC + c];
        float wv3 = Wfuse[(i + 3) * CC + c];
        #pragma unroll
        for (int j = 0; j < NPB / 2; ++j) {
            int ni = half * (NPB / 2) + j;
            float4 hv = *reinterpret_cast<const float4*>(&hbuf[ni][i]);
            acc[j] = fmaf(hv.x, wv0, fmaf(hv.y, wv1,
                     fmaf(hv.z, wv2, fmaf(hv.w, wv3, acc[j]))));
        }
    }
    #pragma unroll
    for (int j = 0; j < NPB / 2; ++j) {
        int n = n0 + half * (NPB / 2) + j;
        if (n < N) out[n * CC + c] = fmaxf(acc[j], 0.f);
    }
}

extern "C" void kernel_launch(void* const* d_in, const int* in_sizes, int n_in,
                              void* d_out, int out_size, void* d_ws, size_t ws_size,
                              hipStream_t stream) {
    const float* x      = (const float*)d_in[0];
    const int*   ei     = (const int*)d_in[1];
    const float* eattr  = (const float*)d_in[2];
    const float* Wsrc0  = (const float*)d_in[3];
    const float* bsrc0  = (const float*)d_in[4];
    const float* Wdst0  = (const float*)d_in[5];
    const float* bdst0  = (const float*)d_in[6];
    const float* Wedge0 = (const float*)d_in[7];
    const float* att0   = (const float*)d_in[8];
    const float* bias0  = (const float*)d_in[9];
    const float* Wres0  = (const float*)d_in[10];
    const float* Wsrc1  = (const float*)d_in[11];
    const float* bsrc1  = (const float*)d_in[12];
    const float* Wdst1  = (const float*)d_in[13];
    const float* bdst1  = (const float*)d_in[14];
    const float* Wedge1 = (const float*)d_in[15];
    const float* att1   = (const float*)d_in[16];
    const float* bias1  = (const float*)d_in[17];
    const float* Wres1  = (const float*)d_in[18];
    const float* Wfuse  = (const float*)d_in[19];
    const float* bfuse  = (const float*)d_in[20];
    float* out = (float*)d_out;

    int N = in_sizes[0] / 2;   // x is (N,2)
    int E = in_sizes[1] / 2;   // edge_index is (2,E)
    int Etot = E + N;
    int EtotPad = (Etot + 511) & ~511;

    // workspace layout; zero region = meansum(0..4) + cnt
    size_t off = 0;
    float* meansum = (float*)((char*)d_ws + off);  off += 256;
    int*   cnt     = (int*)((char*)d_ws + off);    off += roundup256((size_t)N * sizeof(int));
    size_t zero_bytes = off;
    float* Lin     = (float*)((char*)d_ws + off);  off += 256;
    int*   cur     = (int*)((char*)d_ws + off);    off += roundup256((size_t)N * sizeof(int));
    int*   rowptr  = (int*)((char*)d_ws + off);    off += roundup256((size_t)(N + 1) * sizeof(int));
    float* packed  = (float*)((char*)d_ws + off);  off += roundup256(8 * 128 * 8 * sizeof(float));
    float4* ed4    = (float4*)((char*)d_ws + off); off += roundup256((size_t)EtotPad * sizeof(float4));
    float* ea1     = (float*)((char*)d_ws + off);  off += roundup256((size_t)EtotPad * sizeof(float));
    float* p8      = (float*)((char*)d_ws + off);  off += roundup256((size_t)EtotPad * 8 * sizeof(float));
    float* S       = (float*)((char*)d_ws + off);  off += roundup256((size_t)24 * N * sizeof(float));

    hipMemsetAsync(d_ws, 0, zero_bytes, stream);

    prep_kernel<<<(E + 255) / 256, 256, 0, stream>>>(
        ei, eattr, meansum, Lin, cnt,
        Wsrc0, bsrc0, Wdst0, bdst0, Wedge0, att0,
        Wsrc1, bsrc1, Wdst1, bdst1, Wedge1, att1,
        packed, E);

    scan_kernel<<<1, 1024, 0, stream>>>(cnt, rowptr, cur, N);

    scatter_kernel<<<(Etot + 255) / 256, 256, 0, stream>>>(
        ei, x, eattr, meansum, cur, ed4, ea1, N, E);

    int nblk = EtotPad / 512;
    logits_kernel<<<nblk, 256, 0, stream>>>(
        ed4, ea1, Lin, (const float4*)packed, p8, EtotPad);

    nodeS_kernel<<<(N + 31) / 32, 256, 0, stream>>>(rowptr, ed4, p8, S, N);

    node_kernel<<<(N + NPB - 1) / NPB, 256, 0, stream>>>(
        x, S,
        Wsrc0, bsrc0, bias0, Wres0,
        Wsrc1, bsrc1, bias1, Wres1,
        Wfuse, bfuse, out, N);
}